// Round 4
// baseline (213.280 us; speedup 1.0000x reference)
//
#include <hip/hip_runtime.h>

#define DIN 512
#define DOUT 512

typedef int v4i __attribute__((ext_vector_type(4)));
typedef float v4f __attribute__((ext_vector_type(4)));

// exact-divide quantize (weights path, matches ref bit-for-bit)
__device__ __forceinline__ int q8f(float v, float s) {
    int i = (int)rintf(v / s);
    i = i < -128 ? -128 : (i > 127 ? 127 : i);
    return i & 255;
}
// multiply-by-reciprocal quantize (activation path; flip prob ~2^-22, contribution ~0.005 << 0.0525)
__device__ __forceinline__ int q8m(float v, float inv) {
    int i = (int)rintf(v * inv);
    i = i < -128 ? -128 : (i > 127 ? 127 : i);
    return i & 255;
}

// ---------------- Kernel 1: global absmax of x ----------------
__global__ void absmax_kernel(const float4* __restrict__ x4, unsigned* __restrict__ amax, int n4) {
    float m = 0.f;
    int stride = gridDim.x * blockDim.x;
    for (int i = blockIdx.x * blockDim.x + threadIdx.x; i < n4; i += stride) {
        float4 v = x4[i];
        m = fmaxf(m, fmaxf(fmaxf(fabsf(v.x), fabsf(v.y)), fmaxf(fabsf(v.z), fabsf(v.w))));
    }
#pragma unroll
    for (int off = 32; off; off >>= 1) m = fmaxf(m, __shfl_xor(m, off));
    __shared__ float sm[4];
    int lane = threadIdx.x & 63, w = threadIdx.x >> 6;
    if (lane == 0) sm[w] = m;
    __syncthreads();
    if (threadIdx.x == 0) {
        m = fmaxf(fmaxf(sm[0], sm[1]), fmaxf(sm[2], sm[3]));
        atomicMax(amax, __float_as_uint(m));  // positive floats: uint compare == float compare
    }
}

// ---------------- Kernel 2: per-row weight quant ----------------
__global__ void quantw_kernel(const float* __restrict__ w,
                              char* __restrict__ wq, float* __restrict__ wsc) {
    int gid = blockIdx.x * blockDim.x + threadIdx.x;
    int row = gid >> 6, lane = gid & 63;
    const float4* r4 = (const float4*)(w + (long)row * DIN);
    float4 a = r4[lane * 2];
    float4 b = r4[lane * 2 + 1];
    float m = fmaxf(fmaxf(fmaxf(fabsf(a.x), fabsf(a.y)), fmaxf(fabsf(a.z), fabsf(a.w))),
                    fmaxf(fmaxf(fabsf(b.x), fabsf(b.y)), fmaxf(fabsf(b.z), fabsf(b.w))));
#pragma unroll
    for (int off = 32; off; off >>= 1) m = fmaxf(m, __shfl_xor(m, off));
    float s = m / 127.0f;
    int lo = q8f(a.x, s) | (q8f(a.y, s) << 8) | (q8f(a.z, s) << 16) | (q8f(a.w, s) << 24);
    int hi = q8f(b.x, s) | (q8f(b.y, s) << 8) | (q8f(b.z, s) << 16) | (q8f(b.w, s) << 24);
    ((int2*)(wq + (long)row * DIN))[lane] = make_int2(lo, hi);
    if (lane == 0) wsc[row] = s;
}

// ---------------- Kernel 3: barrier-free per-wave GEMM ----------------
// Each WAVE owns 16 m-rows x 512 oc. x loaded coalesced (128B/row/instr),
// quantized into a wave-PRIVATE 8KB LDS slot (no cross-wave sharing -> no
// barriers anywhere; wave-local lgkm ordering suffices). B-frags (x) pulled
// once into 32 VGPRs; A-frags (w) streamed from L2 (wq=256KB, L2-resident)
// through 256 MFMAs, 4 interleaved accumulator chains, 1-step prefetch.
// acc128 + xq32 + wf32 + addr ~= 210 VGPR -> 2 waves/SIMD.
__global__ __launch_bounds__(256, 2) void gemm_kernel(
    const float* __restrict__ x, const char* __restrict__ wq,
    const float* __restrict__ wsc, const float* __restrict__ bias,
    const unsigned* __restrict__ amax, float* __restrict__ out) {
    __shared__ char xs[4][8192];
    const int t = threadIdx.x, lane = t & 63, wid = t >> 6;
    const long rbase = ((long)blockIdx.x * 4 + wid) * 16;
    const float as = __uint_as_float(*amax) / 127.0f;
    const float inv_as = 1.0f / as;
    char* slot = xs[wid];

    // ---- stage: coalesced x load -> quantize -> chunk-linear LDS slot
    // chunk(kc,row) at byte (kc*16+row)*16 ; frag(ks) read = (ks*4+(l>>4))*256+(l&15)*16
    const int srow = lane >> 3, sf4 = lane & 7;
    const float4* xg = (const float4*)(x + (rbase + srow) * DIN) + sf4;
#pragma unroll
    for (int jj = 0; jj < 2; jj++) {
        float4 v[16];
#pragma unroll
        for (int j = 0; j < 16; j++) v[j] = xg[jj * 1024 + j * 8];
#pragma unroll
        for (int j = 0; j < 16; j++) {
            int f4 = sf4 + j * 8;
            int q = q8m(v[j].x, inv_as) | (q8m(v[j].y, inv_as) << 8) |
                    (q8m(v[j].z, inv_as) << 16) | (q8m(v[j].w, inv_as) << 24);
            *(int*)(slot + ((f4 >> 2) * 16 + srow + jj * 8) * 16 + (f4 & 3) * 4) = q;
        }
    }

    // ---- B-fragments (compiler orders ds_write->ds_read via lgkmcnt; wave-local)
    v4i xq[8];
#pragma unroll
    for (int ks = 0; ks < 8; ks++)
        xq[ks] = *(const v4i*)(slot + (ks * 4 + (lane >> 4)) * 256 + (lane & 15) * 16);

    // ---- stream w: 8 oc-groups x 8 ksteps x 4 frags
    const int vbase = (lane & 15) * DIN + (lane >> 4) * 16;
    int vo0 = vbase, vo1 = vbase + 8192, vo2 = vbase + 16384, vo3 = vbase + 24576;
    v4i wf[2][4];
    v4i acc[32] = {};
    wf[0][0] = *(const v4i*)(wq + vo0);
    wf[0][1] = *(const v4i*)(wq + vo1);
    wf[0][2] = *(const v4i*)(wq + vo2);
    wf[0][3] = *(const v4i*)(wq + vo3);
#pragma unroll
    for (int g = 0; g < 8; g++) {
#pragma unroll
        for (int ks = 0; ks < 8; ks++) {
            const int p = ks & 1;
            if (ks < 7) {
                wf[p ^ 1][0] = *(const v4i*)(wq + vo0 + (ks + 1) * 64);
                wf[p ^ 1][1] = *(const v4i*)(wq + vo1 + (ks + 1) * 64);
                wf[p ^ 1][2] = *(const v4i*)(wq + vo2 + (ks + 1) * 64);
                wf[p ^ 1][3] = *(const v4i*)(wq + vo3 + (ks + 1) * 64);
            } else {
                vo0 += 32768; vo1 += 32768; vo2 += 32768; vo3 += 32768;
                if (g < 7) {
                    wf[p ^ 1][0] = *(const v4i*)(wq + vo0);
                    wf[p ^ 1][1] = *(const v4i*)(wq + vo1);
                    wf[p ^ 1][2] = *(const v4i*)(wq + vo2);
                    wf[p ^ 1][3] = *(const v4i*)(wq + vo3);
                }
            }
            acc[g * 4 + 0] = __builtin_amdgcn_mfma_i32_16x16x64_i8(wf[p][0], xq[ks], acc[g * 4 + 0], 0, 0, 0);
            acc[g * 4 + 1] = __builtin_amdgcn_mfma_i32_16x16x64_i8(wf[p][1], xq[ks], acc[g * 4 + 1], 0, 0, 0);
            acc[g * 4 + 2] = __builtin_amdgcn_mfma_i32_16x16x64_i8(wf[p][2], xq[ks], acc[g * 4 + 2], 0, 0, 0);
            acc[g * 4 + 3] = __builtin_amdgcn_mfma_i32_16x16x64_i8(wf[p][3], xq[ks], acc[g * 4 + 3], 0, 0, 0);
        }
    }

    // ---- epilogue: D row = oc (lane>>4)*4+r (4 consecutive oc), col = m (lane&15)
    const int mloc = lane & 15;
    float* orow = out + (rbase + mloc) * DOUT;
#pragma unroll
    for (int ni = 0; ni < 32; ni++) {
        // acc[ni] was built as acc[g*4+i] with oc-base ni*16 (vo_i = i*8192 + g*32768)
        int oc0 = ni * 16 + (lane >> 4) * 4;
        float4 w4 = *(const float4*)(wsc + oc0);
        float4 b4 = *(const float4*)(bias + oc0);
        float bs0 = as * w4.x, bs1 = as * w4.y, bs2 = as * w4.z, bs3 = as * w4.w;
        v4f v;
        v[0] = (float)acc[ni][0] * bs0 + rintf(b4.x / bs0) * bs0;
        v[1] = (float)acc[ni][1] * bs1 + rintf(b4.y / bs1) * bs1;
        v[2] = (float)acc[ni][2] * bs2 + rintf(b4.z / bs2) * bs2;
        v[3] = (float)acc[ni][3] * bs3 + rintf(b4.w / bs3) * bs3;
        __builtin_nontemporal_store(v, (v4f*)(orow + oc0));
    }
}

extern "C" void kernel_launch(void* const* d_in, const int* in_sizes, int n_in,
                              void* d_out, int out_size, void* d_ws, size_t ws_size,
                              hipStream_t stream) {
    const float* x    = (const float*)d_in[0];
    const float* w    = (const float*)d_in[1];
    const float* bias = (const float*)d_in[2];
    float* out = (float*)d_out;
    const int M = in_sizes[0] / DIN;   // 65536

    char* ws = (char*)d_ws;
    unsigned* amax = (unsigned*)ws;
    char* wq   = ws + 64;
    float* wsc = (float*)(ws + 64 + (long)DOUT * DIN);

    hipMemsetAsync(d_ws, 0, 64, stream);
    quantw_kernel<<<(DOUT * 64) / 256, 256, 0, stream>>>(w, wq, wsc);
    absmax_kernel<<<2048, 256, 0, stream>>>((const float4*)x, amax, in_sizes[0] / 4);
    gemm_kernel<<<M / 64, 256, 0, stream>>>(x, wq, wsc, bias, amax, out);
}

// Round 5
// 142.485 us; speedup vs baseline: 1.4969x; 1.4969x over previous
//
#include <hip/hip_runtime.h>

#define DIN 512
#define DOUT 512
#define BM 32

typedef int v4i __attribute__((ext_vector_type(4)));
typedef float v4f __attribute__((ext_vector_type(4)));

// exact-divide quantize (weights path, matches ref bit-for-bit)
__device__ __forceinline__ int q8f(float v, float s) {
    int i = (int)rintf(v / s);
    i = i < -128 ? -128 : (i > 127 ? 127 : i);
    return i & 255;
}
// multiply-by-reciprocal quantize (activation path; flip prob ~2^-22, contribution ~0.005 << 0.0525)
__device__ __forceinline__ int q8m(float v, float inv) {
    int i = (int)rintf(v * inv);
    i = i < -128 ? -128 : (i > 127 ? 127 : i);
    return i & 255;
}

// ---------------- Kernel 1: global absmax of x ----------------
__global__ void absmax_kernel(const float4* __restrict__ x4, unsigned* __restrict__ amax, int n4) {
    float m = 0.f;
    int stride = gridDim.x * blockDim.x;
    for (int i = blockIdx.x * blockDim.x + threadIdx.x; i < n4; i += stride) {
        float4 v = x4[i];
        m = fmaxf(m, fmaxf(fmaxf(fabsf(v.x), fabsf(v.y)), fmaxf(fabsf(v.z), fabsf(v.w))));
    }
#pragma unroll
    for (int off = 32; off; off >>= 1) m = fmaxf(m, __shfl_xor(m, off));
    __shared__ float sm[4];
    int lane = threadIdx.x & 63, w = threadIdx.x >> 6;
    if (lane == 0) sm[w] = m;
    __syncthreads();
    if (threadIdx.x == 0) {
        m = fmaxf(fmaxf(sm[0], sm[1]), fmaxf(sm[2], sm[3]));
        atomicMax(amax, __float_as_uint(m));  // positive floats: uint compare == float compare
    }
}

// ---------------- Kernel 2: per-row weight quant ----------------
__global__ void quantw_kernel(const float* __restrict__ w,
                              char* __restrict__ wq, float* __restrict__ wsc) {
    int gid = blockIdx.x * blockDim.x + threadIdx.x;
    int row = gid >> 6, lane = gid & 63;
    const float4* r4 = (const float4*)(w + (long)row * DIN);
    float4 a = r4[lane * 2];
    float4 b = r4[lane * 2 + 1];
    float m = fmaxf(fmaxf(fmaxf(fabsf(a.x), fabsf(a.y)), fmaxf(fabsf(a.z), fabsf(a.w))),
                    fmaxf(fmaxf(fabsf(b.x), fabsf(b.y)), fmaxf(fabsf(b.z), fabsf(b.w))));
#pragma unroll
    for (int off = 32; off; off >>= 1) m = fmaxf(m, __shfl_xor(m, off));
    float s = m / 127.0f;
    int lo = q8f(a.x, s) | (q8f(a.y, s) << 8) | (q8f(a.z, s) << 16) | (q8f(a.w, s) << 24);
    int hi = q8f(b.x, s) | (q8f(b.y, s) << 8) | (q8f(b.z, s) << 16) | (q8f(b.w, s) << 24);
    ((int2*)(wq + (long)row * DIN))[lane] = make_int2(lo, hi);
    if (lane == 0) wsc[row] = s;
}

// ---------------- Kernel 3: one-barrier burst GEMM ----------------
// BM=32, BN=512 (x read once). 512 thr = 8 waves; wave = 32m x 64oc -> acc 32 VGPR.
// Prologue: whole 64KB x-tile in one 8-load burst/thread -> quant -> LDS (16KB,
// chunk-linear), ONE barrier. Main loop: 8 k-steps, no barriers: 2 ds_read_b128
// (x frags, conflict-free) + 4 wq loads (L2-resident, 2 steps ahead, 3-set
// rotation, static indices) + 8 MFMA. 4 waves/SIMD hides L2/LDS latency.
// Epilogue: swapped-D layout -> 4 consecutive oc per lane -> float4 nt-stores.
__global__ __launch_bounds__(512, 4) void gemm_kernel(
    const float* __restrict__ x, const char* __restrict__ wq,
    const float* __restrict__ wsc, const float* __restrict__ bias,
    const unsigned* __restrict__ amax, float* __restrict__ out) {
    __shared__ char xs[BM * DIN];   // 16 KB int8, chunk(kc,row) at (kc*32+row)*16
    const int t = threadIdx.x, lane = t & 63, wid = t >> 6;
    const long rbase = (long)(gridDim.x - 1 - blockIdx.x) * BM;  // reverse: L3 recency
    const float as = __uint_as_float(*amax) / 127.0f;
    const float inv_as = 1.0f / as;

    // ---- prologue: burst-load 32x512 fp32 (8 float4/thread), quantize, stage
    const int srow = t >> 4, sc = t & 15;
    const float4* xg = (const float4*)(x + (rbase + srow) * DIN) + sc;
    float4 xv[8];
#pragma unroll
    for (int j = 0; j < 8; j++) xv[j] = xg[j * 16];
    char* wrb = xs + srow * 16 + (sc & 3) * 4;
#pragma unroll
    for (int j = 0; j < 8; j++) {
        int kc = (sc >> 2) + j * 4;
        int q = q8m(xv[j].x, inv_as) | (q8m(xv[j].y, inv_as) << 8) |
                (q8m(xv[j].z, inv_as) << 16) | (q8m(xv[j].w, inv_as) << 24);
        *(int*)(wrb + kc * 512) = q;
    }
    __syncthreads();   // the only barrier

    // ---- main loop: w streamed from L2, x frags from LDS
    const char* wg = wq + (wid * 64 + (lane & 15)) * DIN + (lane >> 4) * 16;
    const char* rb = xs + ((lane >> 4) * 32 + (lane & 15)) * 16;  // + ks*2048 + mi*256
    v4i wf[3][4];
    v4i acc[2][4] = {};
#pragma unroll
    for (int ni = 0; ni < 4; ni++) wf[0][ni] = *(const v4i*)(wg + ni * 16 * DIN);
#pragma unroll
    for (int ni = 0; ni < 4; ni++) wf[1][ni] = *(const v4i*)(wg + ni * 16 * DIN + 64);
#pragma unroll
    for (int ks = 0; ks < 8; ks++) {
        if (ks + 2 < 8) {
            const int s2 = (ks + 2) % 3;
#pragma unroll
            for (int ni = 0; ni < 4; ni++)
                wf[s2][ni] = *(const v4i*)(wg + ni * 16 * DIN + (ks + 2) * 64);
        }
        v4i b0 = *(const v4i*)(rb + ks * 2048);
        v4i b1 = *(const v4i*)(rb + ks * 2048 + 256);
        const int s = ks % 3;
#pragma unroll
        for (int ni = 0; ni < 4; ni++) {
            acc[0][ni] = __builtin_amdgcn_mfma_i32_16x16x64_i8(wf[s][ni], b0, acc[0][ni], 0, 0, 0);
            acc[1][ni] = __builtin_amdgcn_mfma_i32_16x16x64_i8(wf[s][ni], b1, acc[1][ni], 0, 0, 0);
        }
    }

    // ---- epilogue: D row = oc local (lane>>4)*4+r, col = m local lane&15
    const int mloc = lane & 15;
    const int ocr = (lane >> 4) * 4;
#pragma unroll
    for (int ni = 0; ni < 4; ni++) {
        int oc0 = wid * 64 + ni * 16 + ocr;
        float4 w4 = *(const float4*)(wsc + oc0);
        float4 b4 = *(const float4*)(bias + oc0);
        float bs0 = as * w4.x, bs1 = as * w4.y, bs2 = as * w4.z, bs3 = as * w4.w;
        float q0 = rintf(b4.x / bs0) * bs0;
        float q1 = rintf(b4.y / bs1) * bs1;
        float q2 = rintf(b4.z / bs2) * bs2;
        float q3 = rintf(b4.w / bs3) * bs3;
#pragma unroll
        for (int mi = 0; mi < 2; mi++) {
            long m = rbase + mi * 16 + mloc;
            v4f v;
            v[0] = (float)acc[mi][ni][0] * bs0 + q0;
            v[1] = (float)acc[mi][ni][1] * bs1 + q1;
            v[2] = (float)acc[mi][ni][2] * bs2 + q2;
            v[3] = (float)acc[mi][ni][3] * bs3 + q3;
            __builtin_nontemporal_store(v, (v4f*)(out + m * DOUT + oc0));
        }
    }
}

extern "C" void kernel_launch(void* const* d_in, const int* in_sizes, int n_in,
                              void* d_out, int out_size, void* d_ws, size_t ws_size,
                              hipStream_t stream) {
    const float* x    = (const float*)d_in[0];
    const float* w    = (const float*)d_in[1];
    const float* bias = (const float*)d_in[2];
    float* out = (float*)d_out;
    const int M = in_sizes[0] / DIN;   // 65536

    char* ws = (char*)d_ws;
    unsigned* amax = (unsigned*)ws;
    char* wq   = ws + 64;
    float* wsc = (float*)(ws + 64 + (long)DOUT * DIN);

    hipMemsetAsync(d_ws, 0, 64, stream);
    quantw_kernel<<<(DOUT * 64) / 256, 256, 0, stream>>>(w, wq, wsc);
    absmax_kernel<<<2048, 256, 0, stream>>>((const float4*)x, amax, in_sizes[0] / 4);
    gemm_kernel<<<M / BM, 512, 0, stream>>>(x, wq, wsc, bias, amax, out);
}

// Round 6
// 137.941 us; speedup vs baseline: 1.5462x; 1.0329x over previous
//
#include <hip/hip_runtime.h>

#define DIN 512
#define DOUT 512
#define BM 32
#define TPB 4   // tiles per block

typedef int v4i __attribute__((ext_vector_type(4)));
typedef float v4f __attribute__((ext_vector_type(4)));

// exact-divide quantize (weights/bias path, matches ref bit-for-bit)
__device__ __forceinline__ int q8f(float v, float s) {
    int i = (int)rintf(v / s);
    i = i < -128 ? -128 : (i > 127 ? 127 : i);
    return i & 255;
}
// multiply-by-reciprocal quantize (activation path; flip prob ~2^-22, contribution ~0.005 << 0.0525)
__device__ __forceinline__ int q8m(float v, float inv) {
    int i = (int)rintf(v * inv);
    i = i < -128 ? -128 : (i > 127 ? 127 : i);
    return i & 255;
}

// ---------------- Kernel 1: global absmax of x ----------------
__global__ void absmax_kernel(const float4* __restrict__ x4, unsigned* __restrict__ amax, int n4) {
    float m = 0.f;
    int stride = gridDim.x * blockDim.x;
    for (int i = blockIdx.x * blockDim.x + threadIdx.x; i < n4; i += stride) {
        float4 v = x4[i];
        m = fmaxf(m, fmaxf(fmaxf(fabsf(v.x), fabsf(v.y)), fmaxf(fabsf(v.z), fabsf(v.w))));
    }
#pragma unroll
    for (int off = 32; off; off >>= 1) m = fmaxf(m, __shfl_xor(m, off));
    __shared__ float sm[4];
    int lane = threadIdx.x & 63, w = threadIdx.x >> 6;
    if (lane == 0) sm[w] = m;
    __syncthreads();
    if (threadIdx.x == 0) {
        m = fmaxf(fmaxf(sm[0], sm[1]), fmaxf(sm[2], sm[3]));
        atomicMax(amax, __float_as_uint(m));  // positive floats: uint compare == float compare
    }
}

// ---------------- Kernel 2: per-row weight quant ----------------
__global__ void quantw_kernel(const float* __restrict__ w,
                              char* __restrict__ wq, float* __restrict__ wsc) {
    int gid = blockIdx.x * blockDim.x + threadIdx.x;
    int row = gid >> 6, lane = gid & 63;
    const float4* r4 = (const float4*)(w + (long)row * DIN);
    float4 a = r4[lane * 2];
    float4 b = r4[lane * 2 + 1];
    float m = fmaxf(fmaxf(fmaxf(fabsf(a.x), fabsf(a.y)), fmaxf(fabsf(a.z), fabsf(a.w))),
                    fmaxf(fmaxf(fabsf(b.x), fabsf(b.y)), fmaxf(fabsf(b.z), fabsf(b.w))));
#pragma unroll
    for (int off = 32; off; off >>= 1) m = fmaxf(m, __shfl_xor(m, off));
    float s = m / 127.0f;
    int lo = q8f(a.x, s) | (q8f(a.y, s) << 8) | (q8f(a.z, s) << 16) | (q8f(a.w, s) << 24);
    int hi = q8f(b.x, s) | (q8f(b.y, s) << 8) | (q8f(b.z, s) << 16) | (q8f(b.w, s) << 24);
    ((int2*)(wq + (long)row * DIN))[lane] = make_int2(lo, hi);
    if (lane == 0) wsc[row] = s;
}

// ---------------- Kernel 2b: combined scales + quantized bias ----------------
__global__ void quantb_kernel(const float* __restrict__ bias, const float* __restrict__ wsc,
                              const unsigned* __restrict__ amax,
                              float* __restrict__ bs, float* __restrict__ bq) {
    int oc = threadIdx.x;
    float as = __uint_as_float(*amax) / 127.0f;
    float s = as * wsc[oc];
    bs[oc] = s;
    bq[oc] = rintf(bias[oc] / s) * s;
}

// ---------------- Kernel 3: persistent cross-tile-pipelined GEMM ----------------
// 512 blocks x 512 thr; each block owns TPB=4 consecutive BM=32 tiles (BN=512 ->
// x read exactly once). Per tile: quant x-regs -> private LDS slot (4 slots, no
// cross-tile reuse -> 1 raw barrier/tile, lgkmcnt only, NO vmcnt drain), issue
// next tile's 8 HBM loads BEFORE the k-loop so they stay in flight across the
// barrier + k-loop (~3000cy cover). k-loop: w streamed from L2 (256KB resident),
// 1-step ping-pong prefetch; 8 MFMA/kstep (~160cy issue/wave) x 4 waves/SIMD
// hides L2. Epilogue: swapped-D float4 nt-stores, scales/bias precomputed.
__global__ __launch_bounds__(512, 4) void gemm_kernel(
    const float* __restrict__ x, const char* __restrict__ wq,
    const float* __restrict__ bs, const float* __restrict__ bq,
    const unsigned* __restrict__ amax, float* __restrict__ out) {
    __shared__ char xs[TPB][BM * DIN];   // 4 x 16 KB, chunk-linear: [kc][row][16B]
    const int t = threadIdx.x, lane = t & 63, wid = t >> 6;
    const float as = __uint_as_float(*amax) / 127.0f;
    const float inv_as = 1.0f / as;

    const int srow = t >> 4, sc = t & 15;            // staging: row t>>4, float4 col t&15
    const char* wg = wq + (wid * 64 + (lane & 15)) * DIN + (lane >> 4) * 16;
    const int rboff = ((lane >> 4) * 32 + (lane & 15)) * 16;
    const int mloc = lane & 15, ocr = (lane >> 4) * 4;

    // tile m-bases (reverse order globally: L3 recency from absmax sweep)
    long m0s[TPB];
#pragma unroll
    for (int tt = 0; tt < TPB; tt++)
        m0s[tt] = (long)(2047 - ((long)blockIdx.x * TPB + tt)) * BM;

    float4 xv[8];
    // prologue: load tile 0's x
    {
        const float4* xg = (const float4*)(x + (m0s[0] + srow) * DIN) + sc;
#pragma unroll
        for (int j = 0; j < 8; j++) xv[j] = xg[j * 16];
    }

#pragma unroll
    for (int tt = 0; tt < TPB; tt++) {
        const long m0 = m0s[tt];
        // ---- quantize current x-regs into slot tt (8 dword ds_writes)
        char* wrb = xs[tt] + srow * 16 + (sc & 3) * 4;
#pragma unroll
        for (int j = 0; j < 8; j++) {
            int kc = (sc >> 2) + j * 4;
            int q = q8m(xv[j].x, inv_as) | (q8m(xv[j].y, inv_as) << 8) |
                    (q8m(xv[j].z, inv_as) << 16) | (q8m(xv[j].w, inv_as) << 24);
            *(int*)(wrb + kc * 512) = q;
        }
        // ---- issue k-step-0 w loads (L2) pre-barrier
        v4i wf[2][4];
#pragma unroll
        for (int ni = 0; ni < 4; ni++) wf[0][ni] = *(const v4i*)(wg + ni * 16 * DIN);
        // ---- issue NEXT tile's x loads (HBM); they stay outstanding across the
        //      raw barrier and the whole k-loop below
        if (tt + 1 < TPB) {
            const float4* xg = (const float4*)(x + (m0s[tt + 1] + srow) * DIN) + sc;
#pragma unroll
            for (int j = 0; j < 8; j++) xv[j] = xg[j * 16];
        }
        // ---- raw barrier: order ds_writes only, do NOT drain vmcnt
        asm volatile("s_waitcnt lgkmcnt(0)" ::: "memory");
        __builtin_amdgcn_s_barrier();

        // ---- k-loop: 8 steps, w 1-step ping-pong from L2, x frags from LDS
        const char* rb = xs[tt] + rboff;
        v4i acc0[4] = {}, acc1[4] = {};
#pragma unroll
        for (int ks = 0; ks < 8; ks++) {
            if (ks < 7) {
#pragma unroll
                for (int ni = 0; ni < 4; ni++)
                    wf[(ks + 1) & 1][ni] = *(const v4i*)(wg + ni * 16 * DIN + (ks + 1) * 64);
            }
            v4i b0 = *(const v4i*)(rb + ks * 2048);
            v4i b1 = *(const v4i*)(rb + ks * 2048 + 256);
#pragma unroll
            for (int ni = 0; ni < 4; ni++) {
                acc0[ni] = __builtin_amdgcn_mfma_i32_16x16x64_i8(wf[ks & 1][ni], b0, acc0[ni], 0, 0, 0);
                acc1[ni] = __builtin_amdgcn_mfma_i32_16x16x64_i8(wf[ks & 1][ni], b1, acc1[ni], 0, 0, 0);
            }
        }

        // ---- epilogue: D row = oc local (lane>>4)*4+r, col = m local lane&15
#pragma unroll
        for (int ni = 0; ni < 4; ni++) {
            int oc0 = wid * 64 + ni * 16 + ocr;
            float4 s4 = *(const float4*)(bs + oc0);
            float4 q4 = *(const float4*)(bq + oc0);
            v4f v;
            v[0] = (float)acc0[ni][0] * s4.x + q4.x;
            v[1] = (float)acc0[ni][1] * s4.y + q4.y;
            v[2] = (float)acc0[ni][2] * s4.z + q4.z;
            v[3] = (float)acc0[ni][3] * s4.w + q4.w;
            __builtin_nontemporal_store(v, (v4f*)(out + (m0 + mloc) * DOUT + oc0));
            v[0] = (float)acc1[ni][0] * s4.x + q4.x;
            v[1] = (float)acc1[ni][1] * s4.y + q4.y;
            v[2] = (float)acc1[ni][2] * s4.z + q4.z;
            v[3] = (float)acc1[ni][3] * s4.w + q4.w;
            __builtin_nontemporal_store(v, (v4f*)(out + (m0 + 16 + mloc) * DOUT + oc0));
        }
    }
}

extern "C" void kernel_launch(void* const* d_in, const int* in_sizes, int n_in,
                              void* d_out, int out_size, void* d_ws, size_t ws_size,
                              hipStream_t stream) {
    const float* x    = (const float*)d_in[0];
    const float* w    = (const float*)d_in[1];
    const float* bias = (const float*)d_in[2];
    float* out = (float*)d_out;
    const int M = in_sizes[0] / DIN;   // 65536

    char* ws = (char*)d_ws;
    unsigned* amax = (unsigned*)ws;
    char* wq   = ws + 64;
    float* wsc = (float*)(ws + 64 + (long)DOUT * DIN);
    float* bs  = wsc + DOUT;
    float* bq  = bs + DOUT;

    hipMemsetAsync(d_ws, 0, 64, stream);
    quantw_kernel<<<(DOUT * 64) / 256, 256, 0, stream>>>(w, wq, wsc);
    absmax_kernel<<<2048, 256, 0, stream>>>((const float4*)x, amax, in_sizes[0] / 4);
    quantb_kernel<<<1, DOUT, 0, stream>>>(bias, wsc, amax, bs, bq);
    gemm_kernel<<<(M / BM) / TPB, 512, 0, stream>>>(x, wq, bs, bq, amax, out);
}

// Round 7
// 120.575 us; speedup vs baseline: 1.7689x; 1.1440x over previous
//
#include <hip/hip_runtime.h>

#define DIN 512
#define DOUT 512
#define BM 64
#define NK 8

typedef int v4i __attribute__((ext_vector_type(4)));
typedef float v4f __attribute__((ext_vector_type(4)));

#define WAITVM(n) asm volatile("s_waitcnt vmcnt(" #n ")" ::: "memory")
#define WAITLGKM0() asm volatile("s_waitcnt lgkmcnt(0)" ::: "memory")

// exact-divide quantize (weights/bias path, matches ref bit-for-bit)
__device__ __forceinline__ int q8f(float v, float s) {
    int i = (int)rintf(v / s);
    i = i < -128 ? -128 : (i > 127 ? 127 : i);
    return i & 255;
}
// multiply-by-reciprocal quantize (activation path; flip prob ~2^-22)
__device__ __forceinline__ int q8m(float v, float inv) {
    int i = (int)rintf(v * inv);
    i = i < -128 ? -128 : (i > 127 ? 127 : i);
    return i & 255;
}

// ---------------- Kernel 1: global absmax of x ----------------
__global__ void absmax_kernel(const float4* __restrict__ x4, unsigned* __restrict__ amax, int n4) {
    float m = 0.f;
    int stride = gridDim.x * blockDim.x;
    for (int i = blockIdx.x * blockDim.x + threadIdx.x; i < n4; i += stride) {
        float4 v = x4[i];
        m = fmaxf(m, fmaxf(fmaxf(fabsf(v.x), fabsf(v.y)), fmaxf(fabsf(v.z), fabsf(v.w))));
    }
#pragma unroll
    for (int off = 32; off; off >>= 1) m = fmaxf(m, __shfl_xor(m, off));
    __shared__ float sm[4];
    int lane = threadIdx.x & 63, w = threadIdx.x >> 6;
    if (lane == 0) sm[w] = m;
    __syncthreads();
    if (threadIdx.x == 0) {
        m = fmaxf(fmaxf(sm[0], sm[1]), fmaxf(sm[2], sm[3]));
        atomicMax(amax, __float_as_uint(m));  // positive floats: uint compare == float compare
    }
}

// ---------------- Kernel 2: per-row weight quant ----------------
__global__ void quantw_kernel(const float* __restrict__ w,
                              char* __restrict__ wq, float* __restrict__ wsc) {
    int gid = blockIdx.x * blockDim.x + threadIdx.x;
    int row = gid >> 6, lane = gid & 63;
    const float4* r4 = (const float4*)(w + (long)row * DIN);
    float4 a = r4[lane * 2];
    float4 b = r4[lane * 2 + 1];
    float m = fmaxf(fmaxf(fmaxf(fabsf(a.x), fabsf(a.y)), fabsf(a.z)),
                    fmaxf(fmaxf(fabsf(a.w), fabsf(b.x)),
                          fmaxf(fmaxf(fabsf(b.y), fabsf(b.z)), fabsf(b.w))));
#pragma unroll
    for (int off = 32; off; off >>= 1) m = fmaxf(m, __shfl_xor(m, off));
    float s = m / 127.0f;
    int lo = q8f(a.x, s) | (q8f(a.y, s) << 8) | (q8f(a.z, s) << 16) | (q8f(a.w, s) << 24);
    int hi = q8f(b.x, s) | (q8f(b.y, s) << 8) | (q8f(b.z, s) << 16) | (q8f(b.w, s) << 24);
    ((int2*)(wq + (long)row * DIN))[lane] = make_int2(lo, hi);
    if (lane == 0) wsc[row] = s;
}

// ---------------- Kernel 2b: combined scales + quantized bias ----------------
__global__ void quantb_kernel(const float* __restrict__ bias, const float* __restrict__ wsc,
                              const unsigned* __restrict__ amax,
                              float* __restrict__ bs, float* __restrict__ bq) {
    int oc = threadIdx.x;
    float as = __uint_as_float(*amax) / 127.0f;
    float s = as * wsc[oc];
    bs[oc] = s;
    bq[oc] = rintf(bias[oc] / s) * s;
}

// ---------------- Kernel 3: trickle-loaded, counted-vmcnt dbuf GEMM ----------------
// BM=64 x BN=512 (x read once), BK=64. 512 thr / 8 waves (2m x 4oc), wave tile
// 32m x 128oc -> acc 2x8 frags = 64 VGPR. Per kstep: issue 4 global_load_lds
// (w -> LDS dbuf, L2-resident source) + 2 x reg-loads (2 steps ahead), then
// vmcnt(8) [w(ks) landed, 6 newer ops stay in flight] -> 16 MFMA -> vmcnt(6)
// [x(ks+1) landed] -> quant -> ds_write -> lgkmcnt(0) + raw s_barrier.
// vmcnt NEVER drains to 0 until the last step: HBM/L2 stream continuously.
// LDS chunk-linear layouts keep every ds access at base+lane*16 (conflict-free)
// and satisfy global_load_lds's wave-uniform-base+lane*16 constraint.
__global__ __launch_bounds__(512, 4) void gemm_kernel(
    const float* __restrict__ x, const char* __restrict__ wq,
    const float* __restrict__ bs, const float* __restrict__ bq,
    const unsigned* __restrict__ amax, float* __restrict__ out) {
    __shared__ char xl[2][BM * 64];     // 2 x 4 KB
    __shared__ char wl[2][DOUT * 64];   // 2 x 32 KB
    const int t = threadIdx.x, lane = t & 63, wid = t >> 6;
    const int wm = wid >> 2, wn = wid & 3;
    const long rbase = (long)blockIdx.x * BM;
    const float as = __uint_as_float(*amax) / 127.0f;
    const float inv_as = 1.0f / as;

    // x staging geometry: thread t -> row t>>3, float4-pair col (t&7)*2
    const int xrow = t >> 3, xc = t & 7;
    const float4* xg = (const float4*)(x + (rbase + xrow) * DIN) + xc * 2;
    const int xw_off = ((xrow >> 4) * 64 + (xc >> 1) * 16 + (xrow & 15)) * 16 + (xc & 1) * 8;

    // w DMA geometry: wave wid stages oc-groups 4*wid..4*wid+3
    const char* wgsrc = wq + ((wid * 64) + (lane & 15)) * DIN + (lane >> 4) * 16;

    float4 xv[2][2];
    v4i acc[2][8] = {};

#define LOADX(n, s) { const float4* p_ = xg + (n) * 16; xv[s][0] = p_[0]; xv[s][1] = p_[1]; }
#define DMAW(n, b) { _Pragma("unroll") for (int jj = 0; jj < 4; jj++) \
    __builtin_amdgcn_global_load_lds( \
        (const __attribute__((address_space(1))) unsigned*)(wgsrc + jj * 16 * DIN + (n) * 64), \
        (__attribute__((address_space(3))) unsigned*)(wl[b] + (wid * 4 + jj) * 1024), 16, 0, 0); }
#define QUANTX(s, b) { \
    int lo_ = q8m(xv[s][0].x, inv_as) | (q8m(xv[s][0].y, inv_as) << 8) | \
              (q8m(xv[s][0].z, inv_as) << 16) | (q8m(xv[s][0].w, inv_as) << 24); \
    int hi_ = q8m(xv[s][1].x, inv_as) | (q8m(xv[s][1].y, inv_as) << 8) | \
              (q8m(xv[s][1].z, inv_as) << 16) | (q8m(xv[s][1].w, inv_as) << 24); \
    *(int2*)&xl[b][xw_off] = make_int2(lo_, hi_); }
#define COMPUTE(p) { \
    v4i xa0 = *(const v4i*)&xl[p][(wm * 2 + 0) * 1024 + lane * 16]; \
    v4i xa1 = *(const v4i*)&xl[p][(wm * 2 + 1) * 1024 + lane * 16]; \
    _Pragma("unroll") for (int ni = 0; ni < 8; ni++) { \
        v4i wb = *(const v4i*)&wl[p][(wn * 8 + ni) * 1024 + lane * 16]; \
        acc[0][ni] = __builtin_amdgcn_mfma_i32_16x16x64_i8(wb, xa0, acc[0][ni], 0, 0, 0); \
        acc[1][ni] = __builtin_amdgcn_mfma_i32_16x16x64_i8(wb, xa1, acc[1][ni], 0, 0, 0); } }

    // prologue: queue = [x0:2, w0:4, x1:2]
    LOADX(0, 0);
    DMAW(0, 0);
    LOADX(1, 1);
    WAITVM(6);          // x0 landed; w0+x1 in flight
    QUANTX(0, 0);
    WAITLGKM0();
    __builtin_amdgcn_s_barrier();

    // steady steps ks=0..5: entering queue [w(ks):4, x(ks+1):2]
#define STEP_MID(KS, PB) \
    DMAW(KS + 1, PB ^ 1); \
    LOADX(KS + 2, (KS) & 1); \
    WAITVM(8);                       /* w(ks) retired; 8 newer in flight */ \
    COMPUTE(PB); \
    WAITVM(6);                       /* x(ks+1) retired */ \
    QUANTX((KS + 1) & 1, PB ^ 1); \
    WAITLGKM0(); \
    __builtin_amdgcn_s_barrier();

    STEP_MID(0, 0)
    STEP_MID(1, 1)
    STEP_MID(2, 0)
    STEP_MID(3, 1)
    STEP_MID(4, 0)
    STEP_MID(5, 1)
    // ks=6 (p=0): entering [w6:4, x7:2]; issue w7 only
    DMAW(7, 1);
    WAITVM(6);          // w6 retired
    COMPUTE(0);
    WAITVM(4);          // x7 retired
    QUANTX(1, 1);
    WAITLGKM0();
    __builtin_amdgcn_s_barrier();
    // ks=7 (p=1): entering [w7:4]
    WAITVM(0);
    COMPUTE(1);

    // epilogue: D row = oc local (lane>>4)*4+r, col = m local lane&15
    const int mloc = lane & 15, ocr = (lane >> 4) * 4;
#pragma unroll
    for (int ni = 0; ni < 8; ni++) {
        int oc0 = wn * 128 + ni * 16 + ocr;
        float4 s4 = *(const float4*)(bs + oc0);
        float4 q4 = *(const float4*)(bq + oc0);
#pragma unroll
        for (int mi = 0; mi < 2; mi++) {
            long m = rbase + wm * 32 + mi * 16 + mloc;
            v4f v;
            v[0] = (float)acc[mi][ni][0] * s4.x + q4.x;
            v[1] = (float)acc[mi][ni][1] * s4.y + q4.y;
            v[2] = (float)acc[mi][ni][2] * s4.z + q4.z;
            v[3] = (float)acc[mi][ni][3] * s4.w + q4.w;
            __builtin_nontemporal_store(v, (v4f*)(out + m * DOUT + oc0));
        }
    }
#undef LOADX
#undef DMAW
#undef QUANTX
#undef COMPUTE
#undef STEP_MID
}

extern "C" void kernel_launch(void* const* d_in, const int* in_sizes, int n_in,
                              void* d_out, int out_size, void* d_ws, size_t ws_size,
                              hipStream_t stream) {
    const float* x    = (const float*)d_in[0];
    const float* w    = (const float*)d_in[1];
    const float* bias = (const float*)d_in[2];
    float* out = (float*)d_out;
    const int M = in_sizes[0] / DIN;   // 65536

    char* ws = (char*)d_ws;
    unsigned* amax = (unsigned*)ws;
    char* wq   = ws + 64;
    float* wsc = (float*)(ws + 64 + (long)DOUT * DIN);
    float* bs  = wsc + DOUT;
    float* bq  = bs + DOUT;

    hipMemsetAsync(d_ws, 0, 64, stream);
    quantw_kernel<<<(DOUT * 64) / 256, 256, 0, stream>>>(w, wq, wsc);
    absmax_kernel<<<2048, 256, 0, stream>>>((const float4*)x, amax, in_sizes[0] / 4);
    quantb_kernel<<<1, DOUT, 0, stream>>>(bias, wsc, amax, bs, bq);
    gemm_kernel<<<M / BM, 512, 0, stream>>>(x, wq, bs, bq, amax, out);
}

// Round 8
// 109.621 us; speedup vs baseline: 1.9456x; 1.0999x over previous
//
#include <hip/hip_runtime.h>

#define DIN 512
#define DOUT 512
#define BM 64
#define NK 8

typedef int v4i __attribute__((ext_vector_type(4)));
typedef float v4f __attribute__((ext_vector_type(4)));

#define WAITVM(n) asm volatile("s_waitcnt vmcnt(" #n ")" ::: "memory")
#define WAITLGKM0() asm volatile("s_waitcnt lgkmcnt(0)" ::: "memory")

// exact-divide quantize (weights/bias path, matches ref bit-for-bit)
__device__ __forceinline__ int q8f(float v, float s) {
    int i = (int)rintf(v / s);
    i = i < -128 ? -128 : (i > 127 ? 127 : i);
    return i & 255;
}
// multiply-by-reciprocal quantize (activation path; flip prob ~2^-22)
__device__ __forceinline__ int q8m(float v, float inv) {
    int i = (int)rintf(v * inv);
    i = i < -128 ? -128 : (i > 127 ? 127 : i);
    return i & 255;
}

// ---------------- Kernel 1: global absmax of x ----------------
__global__ void absmax_kernel(const float4* __restrict__ x4, unsigned* __restrict__ amax, int n4) {
    float m = 0.f;
    int stride = gridDim.x * blockDim.x;
    for (int i = blockIdx.x * blockDim.x + threadIdx.x; i < n4; i += stride) {
        float4 v = x4[i];
        m = fmaxf(m, fmaxf(fmaxf(fabsf(v.x), fabsf(v.y)), fmaxf(fabsf(v.z), fabsf(v.w))));
    }
#pragma unroll
    for (int off = 32; off; off >>= 1) m = fmaxf(m, __shfl_xor(m, off));
    __shared__ float sm[4];
    int lane = threadIdx.x & 63, w = threadIdx.x >> 6;
    if (lane == 0) sm[w] = m;
    __syncthreads();
    if (threadIdx.x == 0) {
        m = fmaxf(fmaxf(sm[0], sm[1]), fmaxf(sm[2], sm[3]));
        atomicMax(amax, __float_as_uint(m));  // positive floats: uint compare == float compare
    }
}

// ---------------- Kernel 2: per-row weight quant ----------------
__global__ void quantw_kernel(const float* __restrict__ w,
                              char* __restrict__ wq, float* __restrict__ wsc) {
    int gid = blockIdx.x * blockDim.x + threadIdx.x;
    int row = gid >> 6, lane = gid & 63;
    const float4* r4 = (const float4*)(w + (long)row * DIN);
    float4 a = r4[lane * 2];
    float4 b = r4[lane * 2 + 1];
    float m = fmaxf(fmaxf(fmaxf(fabsf(a.x), fabsf(a.y)), fabsf(a.z)),
                    fmaxf(fmaxf(fabsf(a.w), fabsf(b.x)),
                          fmaxf(fmaxf(fabsf(b.y), fabsf(b.z)), fabsf(b.w))));
#pragma unroll
    for (int off = 32; off; off >>= 1) m = fmaxf(m, __shfl_xor(m, off));
    float s = m / 127.0f;
    int lo = q8f(a.x, s) | (q8f(a.y, s) << 8) | (q8f(a.z, s) << 16) | (q8f(a.w, s) << 24);
    int hi = q8f(b.x, s) | (q8f(b.y, s) << 8) | (q8f(b.z, s) << 16) | (q8f(b.w, s) << 24);
    ((int2*)(wq + (long)row * DIN))[lane] = make_int2(lo, hi);
    if (lane == 0) wsc[row] = s;
}

// ---------------- Kernel 2b: combined scales + quantized bias ----------------
__global__ void quantb_kernel(const float* __restrict__ bias, const float* __restrict__ wsc,
                              const unsigned* __restrict__ amax,
                              float* __restrict__ bs, float* __restrict__ bq) {
    int oc = threadIdx.x;
    float as = __uint_as_float(*amax) / 127.0f;
    float s = as * wsc[oc];
    bs[oc] = s;
    bq[oc] = rintf(bias[oc] / s) * s;
}

// ---------------- Kernel 3: trickle GEMM + full-line transposed store ----------------
// K-loop identical to R7 (counted-vmcnt dbuf, never drains in-loop). Epilogue
// rewritten: acc -> (scale,bias) -> 32x512 f32 staging tile in the retired wl
// LDS (XOR-swizzled, 2 rounds by wm), then each wave nt-stores 1KB CONTIGUOUS
// per instruction (sequential 2048B rows) -- eliminates the scattered-64B nt
// write pattern that amplified WRITE_SIZE to 179MB and capped HBM at 3.4TB/s.
__global__ __launch_bounds__(512, 4) void gemm_kernel(
    const float* __restrict__ x, const char* __restrict__ wq,
    const float* __restrict__ bs, const float* __restrict__ bq,
    const unsigned* __restrict__ amax, float* __restrict__ out) {
    __shared__ char xl[2][BM * 64];     // 2 x 4 KB
    __shared__ char wl[2][DOUT * 64];   // 2 x 32 KB (reused as 64KB f32 out-stage)
    const int t = threadIdx.x, lane = t & 63, wid = t >> 6;
    const int wm = wid >> 2, wn = wid & 3;
    const long rbase = (long)blockIdx.x * BM;
    const float as = __uint_as_float(*amax) / 127.0f;
    const float inv_as = 1.0f / as;

    // x staging geometry: thread t -> row t>>3, float4-pair col (t&7)*2
    const int xrow = t >> 3, xc = t & 7;
    const float4* xg = (const float4*)(x + (rbase + xrow) * DIN) + xc * 2;
    const int xw_off = ((xrow >> 4) * 64 + (xc >> 1) * 16 + (xrow & 15)) * 16 + (xc & 1) * 8;

    // w DMA geometry: wave wid stages oc-groups 4*wid..4*wid+3
    const char* wgsrc = wq + ((wid * 64) + (lane & 15)) * DIN + (lane >> 4) * 16;

    float4 xv[2][2];
    v4i acc[2][8] = {};

#define LOADX(n, s) { const float4* p_ = xg + (n) * 16; xv[s][0] = p_[0]; xv[s][1] = p_[1]; }
#define DMAW(n, b) { _Pragma("unroll") for (int jj = 0; jj < 4; jj++) \
    __builtin_amdgcn_global_load_lds( \
        (const __attribute__((address_space(1))) unsigned*)(wgsrc + jj * 16 * DIN + (n) * 64), \
        (__attribute__((address_space(3))) unsigned*)(wl[b] + (wid * 4 + jj) * 1024), 16, 0, 0); }
#define QUANTX(s, b) { \
    int lo_ = q8m(xv[s][0].x, inv_as) | (q8m(xv[s][0].y, inv_as) << 8) | \
              (q8m(xv[s][0].z, inv_as) << 16) | (q8m(xv[s][0].w, inv_as) << 24); \
    int hi_ = q8m(xv[s][1].x, inv_as) | (q8m(xv[s][1].y, inv_as) << 8) | \
              (q8m(xv[s][1].z, inv_as) << 16) | (q8m(xv[s][1].w, inv_as) << 24); \
    *(int2*)&xl[b][xw_off] = make_int2(lo_, hi_); }
#define COMPUTE(p) { \
    v4i xa0 = *(const v4i*)&xl[p][(wm * 2 + 0) * 1024 + lane * 16]; \
    v4i xa1 = *(const v4i*)&xl[p][(wm * 2 + 1) * 1024 + lane * 16]; \
    _Pragma("unroll") for (int ni = 0; ni < 8; ni++) { \
        v4i wb = *(const v4i*)&wl[p][(wn * 8 + ni) * 1024 + lane * 16]; \
        acc[0][ni] = __builtin_amdgcn_mfma_i32_16x16x64_i8(wb, xa0, acc[0][ni], 0, 0, 0); \
        acc[1][ni] = __builtin_amdgcn_mfma_i32_16x16x64_i8(wb, xa1, acc[1][ni], 0, 0, 0); } }

    // prologue: queue = [x0:2, w0:4, x1:2]
    LOADX(0, 0);
    DMAW(0, 0);
    LOADX(1, 1);
    WAITVM(6);          // x0 landed; w0+x1 in flight
    QUANTX(0, 0);
    WAITLGKM0();
    __builtin_amdgcn_s_barrier();

#define STEP_MID(KS, PB) \
    DMAW(KS + 1, PB ^ 1); \
    LOADX(KS + 2, (KS) & 1); \
    WAITVM(8);                       /* w(ks) retired; 8 newer in flight */ \
    COMPUTE(PB); \
    WAITVM(6);                       /* x(ks+1) retired */ \
    QUANTX((KS + 1) & 1, PB ^ 1); \
    WAITLGKM0(); \
    __builtin_amdgcn_s_barrier();

    STEP_MID(0, 0)
    STEP_MID(1, 1)
    STEP_MID(2, 0)
    STEP_MID(3, 1)
    STEP_MID(4, 0)
    STEP_MID(5, 1)
    // ks=6 (p=0): entering [w6:4, x7:2]; issue w7 only
    DMAW(7, 1);
    WAITVM(6);          // w6 retired
    COMPUTE(0);
    WAITVM(4);          // x7 retired
    QUANTX(1, 1);
    WAITLGKM0();
    __builtin_amdgcn_s_barrier();
    // ks=7 (p=1): entering [w7:4]
    WAITVM(0);
    COMPUTE(1);

    // ---- epilogue: LDS-transposed full-line nt stores ----
    // round h: waves with wm==h scale+write rows [h*32, h*32+32) x 512 f32 into
    // ostage (XOR-swizzled); then ALL waves store 1KB-contiguous pieces.
    __builtin_amdgcn_s_barrier();   // all waves done reading wl/xl
    char* ostage = (char*)wl;       // 32 x 2048B rows = 64 KB
    const int mloc = lane & 15, ocr = (lane >> 4) * 4;
    const char* outb = (char*)out + rbase * 2048 + t * 16;
#pragma unroll
    for (int h = 0; h < 2; h++) {
        if (wm == h) {
#pragma unroll
            for (int ni = 0; ni < 8; ni++) {
                int oc0 = wn * 128 + ni * 16 + ocr;
                float4 s4 = *(const float4*)(bs + oc0);
                float4 q4 = *(const float4*)(bq + oc0);
#pragma unroll
                for (int mi = 0; mi < 2; mi++) {
                    int row = mi * 16 + mloc;
                    v4f v;
                    v[0] = (float)acc[mi][ni][0] * s4.x + q4.x;
                    v[1] = (float)acc[mi][ni][1] * s4.y + q4.y;
                    v[2] = (float)acc[mi][ni][2] * s4.z + q4.z;
                    v[3] = (float)acc[mi][ni][3] * s4.w + q4.w;
                    int byte = (row * 2048 + oc0 * 4) ^ ((row & 15) << 4);
                    *(v4f*)(ostage + byte) = v;
                }
            }
        }
        WAITLGKM0();
        __builtin_amdgcn_s_barrier();
#pragma unroll
        for (int i = 0; i < 8; i++) {
            int flat = t * 16 + i * 8192;
            int row = flat >> 11;
            v4f v = *(const v4f*)(ostage + (flat ^ ((row & 15) << 4)));
            __builtin_nontemporal_store(v, (v4f*)(outb + h * 65536 + i * 8192));
        }
        if (h == 0) {
            WAITLGKM0();
            __builtin_amdgcn_s_barrier();   // reads done before h=1 overwrites
        }
    }
#undef LOADX
#undef DMAW
#undef QUANTX
#undef COMPUTE
#undef STEP_MID
}

extern "C" void kernel_launch(void* const* d_in, const int* in_sizes, int n_in,
                              void* d_out, int out_size, void* d_ws, size_t ws_size,
                              hipStream_t stream) {
    const float* x    = (const float*)d_in[0];
    const float* w    = (const float*)d_in[1];
    const float* bias = (const float*)d_in[2];
    float* out = (float*)d_out;
    const int M = in_sizes[0] / DIN;   // 65536

    char* ws = (char*)d_ws;
    unsigned* amax = (unsigned*)ws;
    char* wq   = ws + 64;
    float* wsc = (float*)(ws + 64 + (long)DOUT * DIN);
    float* bs  = wsc + DOUT;
    float* bq  = bs + DOUT;

    hipMemsetAsync(d_ws, 0, 64, stream);
    quantw_kernel<<<(DOUT * 64) / 256, 256, 0, stream>>>(w, wq, wsc);
    absmax_kernel<<<2048, 256, 0, stream>>>((const float4*)x, amax, in_sizes[0] / 4);
    quantb_kernel<<<1, DOUT, 0, stream>>>(bias, wsc, amax, bs, bq);
    gemm_kernel<<<M / BM, 512, 0, stream>>>(x, wq, bs, bq, amax, out);
}